// Round 6
// baseline (770.827 us; speedup 1.0000x reference)
//
#include <hip/hip_runtime.h>
#include <hip/hip_bf16.h>
#include <math.h>

typedef unsigned short ushort_t;
typedef __attribute__((ext_vector_type(8))) short bf16x8;
typedef __attribute__((ext_vector_type(4))) float f32x4;

// ---------------- problem constants ----------------
#define NHQ 24             // 8 heads * 3 queries
#define LN_EPS 1e-5f
#define NBLK_F 469         // fused fallback blocks (128 p each)
#define NBLK_P 938         // proj/attn blocks (64 p each)

// ---------------- workspace layout (float offsets) ----------------
#define WS_BAG 0                        // 1536
#define WS_SEL 1536                     // 768
#define WS_GENE 2304                    // 256
#define WS_PM 3584                      // 1024*24
#define WS_PL 28160                     // 1024*24
#define WS_PACC 52736                   // 1024*768
#define WS_PPOOL 839168                 // 1024*768
#define WS_ATTN 1625600                 // 768
#define WS_POOLED 1626368               // 768
#define WS_BF16 1627136                 // ushort region start (byte ofs %16==0)
// ushort offsets inside bf16 region
#define U_WPT 0                         // wp packed: 16 D16 * 32 K32 * 512
#define U_WKT 262144                    // 16 * 8 * 512
#define U_WVT 327680
#define U_QB  393216                    // 24*32 q bf16 (pre-scaled)
#define U_WSIP 401408                   // wsi packed: 3752 p16 * 4096
#define WS_SPLIT_BYTES 38047744ULL

// ---------------- helpers ----------------
__device__ __forceinline__ ushort_t f2bf(float f) {
    __hip_bfloat16 h = __float2bfloat16(f);
    return *reinterpret_cast<ushort_t*>(&h);
}
__device__ __forceinline__ float bf2f(unsigned int u) {
    union { unsigned int i; float f; } c; c.i = u << 16; return c.f;
}
__device__ __forceinline__ unsigned int pk2(float a, float b) {
    return (unsigned int)f2bf(a) | ((unsigned int)f2bf(b) << 16);
}

// ---------------- prep: weights -> bf16 fragment-packed ----------------
__global__ void prep_kernel(const float* __restrict__ wp, const float* __restrict__ wk,
                            const float* __restrict__ wv, ushort_t* __restrict__ ub) {
    const int b = blockIdx.x, t = threadIdx.x;
    if (b < 16) {
        const int D16 = b;
        for (int i = 0; i < 64; ++i) {
            int f = t + i * 256;
            int K32 = f >> 9, r = f & 511;
            int lg = r >> 7, lm2 = (r >> 3) & 15, e = r & 7;
            int k = K32 * 32 + lg * 8 + e, d = D16 * 16 + lm2;
            ub[U_WPT + D16 * 16384 + f] = f2bf(wp[(size_t)k * 256 + d]);
        }
    } else if (b < 32) {
        const int D16 = b - 16;
        for (int i = 0; i < 16; ++i) {
            int f = t + i * 256;
            int K32 = f >> 9, r = f & 511;
            int lg = r >> 7, lm2 = (r >> 3) & 15, e = r & 7;
            int k = K32 * 32 + lg * 8 + e, d = D16 * 16 + lm2;
            ub[U_WKT + D16 * 4096 + f] = f2bf(wk[(size_t)k * 256 + d]);
        }
    } else {
        const int D16 = b - 32;
        for (int i = 0; i < 16; ++i) {
            int f = t + i * 256;
            int K32 = f >> 9, r = f & 511;
            int lg = r >> 7, lm2 = (r >> 3) & 15, e = r & 7;
            int k = K32 * 32 + lg * 8 + e, d = D16 * 16 + lm2;
            ub[U_WVT + D16 * 4096 + f] = f2bf(wv[(size_t)k * 256 + d]);
        }
    }
}

struct PrepArgs {
    const float* xo[6];
    const float* w1[6];
    int sz[6];
};

// ---------------- per-pathway SNN ----------------
__global__ void snn_kernel(PrepArgs pa, const float* __restrict__ sb1,
                           const float* __restrict__ sw2, const float* __restrict__ sb2,
                           float* __restrict__ bag) {
    __shared__ float xsh[600];
    __shared__ float t1sh[256];
    const int i = blockIdx.x;
    const int t = threadIdx.x;
    const int s = pa.sz[i];
    const float* xo = pa.xo[i];
    const float* w1 = pa.w1[i];
    for (int j = t; j < s; j += 256) xsh[j] = xo[j];
    __syncthreads();
    float acc = sb1[i * 256 + t];
    for (int j = 0; j < s; ++j) acc += xsh[j] * w1[j * 256 + t];
    t1sh[t] = acc > 0.f ? acc : expm1f(acc);
    __syncthreads();
    float acc2 = sb2[i * 256 + t];
    const float* w2 = sw2 + (size_t)i * 256 * 256;
    for (int j = 0; j < 256; ++j) acc2 += t1sh[j] * w2[j * 256 + t];
    bag[i * 256 + t] = acc2 > 0.f ? acc2 : expm1f(acc2);
}

// ---------------- gene scores, top-3 select, q projection (-> bf16) ----------------
__global__ void select_kernel(const float* __restrict__ wa1, const float* __restrict__ ba1,
                              const float* __restrict__ wa2, const float* __restrict__ ba2,
                              const float* __restrict__ wq, const float* __restrict__ bq,
                              float* __restrict__ wsf, ushort_t* __restrict__ ub) {
    __shared__ float bsh[6][256];
    __shared__ float ysh[64];
    __shared__ float ssh[8];
    __shared__ int isel[3];
    const int t = threadIdx.x;
    for (int j = t; j < 1536; j += 256) ((float*)bsh)[j] = wsf[WS_BAG + j];
    __syncthreads();
    for (int i = 0; i < 6; ++i) {
        if (t < 64) {
            float acc = ba1[t];
            for (int j = 0; j < 256; ++j) acc += bsh[i][j] * wa1[j * 64 + t];
            ysh[t] = fmaxf(acc, 0.f) * wa2[t];
        }
        __syncthreads();
        if (t == 0) {
            float sc = ba2[0];
            for (int j = 0; j < 64; ++j) sc += ysh[j];
            ssh[i] = sc;
        }
        __syncthreads();
    }
    if (t == 0) {
        float sc[6];
        for (int i = 0; i < 6; ++i) sc[i] = ssh[i];
        for (int k = 0; k < 3; ++k) {
            int best = 0; float bv = sc[0];
            for (int i = 1; i < 6; ++i) if (sc[i] > bv) { bv = sc[i]; best = i; }
            isel[k] = best;
            sc[best] = -INFINITY;
        }
    }
    __syncthreads();
    float g = 0.f;
    for (int k = 0; k < 3; ++k) {
        float v = bsh[isel[k]][t];
        wsf[WS_SEL + k * 256 + t] = v;
        g += v;
    }
    wsf[WS_GENE + t] = g * (1.f / 3.f);
    for (int kq = 0; kq < 3; ++kq) {
        float acc = bq[t];
        const float* srow = bsh[isel[kq]];
        for (int j = 0; j < 256; ++j) acc += srow[j] * wq[j * 256 + t];
        float v = acc * 0.17677669529663687f;
        int hq = (t >> 5) * 3 + kq, dd = t & 31;
        ub[U_QB + hq * 32 + dd] = f2bf(v);
    }
}

// ================== SPLIT PATH ==================

// ---- proj v2: 938 blocks x 256 thr, 64 patches each; 4 blocks/CU ----
#define P2LOAD_X(xr, c) { \
    _Pragma("unroll") for (int i_ = 0; i_ < 4; ++i_) { \
        int f_ = tid + i_ * 256; int p_ = f_ >> 4, c4_ = f_ & 15; \
        if (n0 + p_ < 60000) \
            xr[i_] = *(const float4*)(xp + (size_t)(n0 + p_) * 1024 + (c) * 64 + c4_ * 4); \
        else { xr[i_].x = 0.f; xr[i_].y = 0.f; xr[i_].z = 0.f; xr[i_].w = 0.f; } } }

#define P2STORE_X(xr, buf) { \
    _Pragma("unroll") for (int i_ = 0; i_ < 4; ++i_) { \
        int f_ = tid + i_ * 256; int p_ = f_ >> 4, c4_ = f_ & 15; \
        int byte_ = (p_ * 128 + c4_ * 8) ^ ((p_ & 7) << 4); \
        uint2 u_; u_.x = pk2(xr[i_].x, xr[i_].y); u_.y = pk2(xr[i_].z, xr[i_].w); \
        *(uint2*)((buf) + byte_) = u_; } }

__global__ __launch_bounds__(256, 4) void proj_kernel(
    const float* __restrict__ xp, const float* __restrict__ bp,
    const ushort_t* __restrict__ ub, ushort_t* __restrict__ wsiP)
{
    __shared__ __align__(16) char xbuf[2][8192];   // 64p x 64k bf16, swz ^((p&7)<<4)
    const int tid = threadIdx.x;
    const int b = blockIdx.x;
    const int lane = tid & 63;
    const int w = tid >> 6;          // wave 0..3 -> d-range w*64
    const int lm = lane & 15;
    const int lg = lane >> 4;
    const int n0 = b * 64;
    const ushort_t* wpP = ub + U_WPT;

    f32x4 acc[16];
#pragma unroll
    for (int i = 0; i < 16; ++i) acc[i] = (f32x4){0.f, 0.f, 0.f, 0.f};

    float4 xr[4];
    P2LOAD_X(xr, 0);
    P2STORE_X(xr, xbuf[0]);
    P2LOAD_X(xr, 1);
    __syncthreads();
#pragma unroll 1
    for (int c = 0; c < 16; ++c) {
        const char* cur = xbuf[c & 1];
        if (c < 15) P2STORE_X(xr, xbuf[(c + 1) & 1]);
        if (c < 14) P2LOAD_X(xr, c + 2);
#pragma unroll
        for (int ks = 0; ks < 2; ++ks) {
            bf16x8 wf[4];
#pragma unroll
            for (int dt = 0; dt < 4; ++dt)
                wf[dt] = *(const bf16x8*)(wpP + ((size_t)((w * 4 + dt) * 32 + c * 2 + ks)) * 512 + lane * 8);
            bf16x8 bfr[4];
#pragma unroll
            for (int pt = 0; pt < 4; ++pt) {
                int p = pt * 16 + lm;
                int byte = (p * 128 + ks * 64 + lg * 16) ^ ((p & 7) << 4);
                bfr[pt] = *(const bf16x8*)(cur + byte);
            }
#pragma unroll
            for (int dt = 0; dt < 4; ++dt)
#pragma unroll
                for (int pt = 0; pt < 4; ++pt)
                    acc[dt * 4 + pt] = __builtin_amdgcn_mfma_f32_16x16x32_bf16(wf[dt], bfr[pt], acc[dt * 4 + pt], 0, 0, 0);
        }
        __syncthreads();
    }
    // epilogue: relu+bias -> packed fragment store
#pragma unroll
    for (int dt = 0; dt < 4; ++dt) {
        int d0 = w * 64 + dt * 16 + lg * 4;
        float4 bb = *(const float4*)(bp + d0);
        int ks2 = d0 >> 5, lg2 = (d0 >> 3) & 3, e0 = d0 & 7;
#pragma unroll
        for (int pt = 0; pt < 4; ++pt) {
            int p16 = b * 4 + pt;
            f32x4 v = acc[dt * 4 + pt];
            uint2 u;
            u.x = pk2(fmaxf(v[0] + bb.x, 0.f), fmaxf(v[1] + bb.y, 0.f));
            u.y = pk2(fmaxf(v[2] + bb.z, 0.f), fmaxf(v[3] + bb.w, 0.f));
            *(uint2*)(wsiP + (size_t)((p16 * 8 + ks2) * 4 + lg2) * 128 + lm * 8 + e0) = u;
        }
    }
}

// ---- attn: k/v proj from packed wsi + single-shot softmax + PV + pool partials ----
__global__ __launch_bounds__(256, 4) void attn_kernel(
    const float* __restrict__ bk, const float* __restrict__ bv,
    const ushort_t* __restrict__ ub, const ushort_t* __restrict__ wsiP,
    float* __restrict__ wsf)
{
    __shared__ __align__(16) ushort_t kv_s[64 * 256];   // k [p][d] swz p ; then vT [d][p] swz d
    __shared__ __align__(16) ushort_t p_s[24 * 64];
    const int tid = threadIdx.x;
    const int b = blockIdx.x;
    const int lane = tid & 63, w = tid >> 6;
    const int lm = lane & 15, lg = lane >> 4;
    const int lmc = lm < 3 ? lm : 2;
    const int n0 = b * 64;
    const int wd0 = w * 64;
    const ushort_t* wkP = ub + U_WKT;
    const ushort_t* wvP = ub + U_WVT;

    // ---- K projection ----
    {
        f32x4 acc[16];
#pragma unroll
        for (int i = 0; i < 16; ++i) acc[i] = (f32x4){0.f, 0.f, 0.f, 0.f};
#pragma unroll
        for (int ks = 0; ks < 8; ++ks) {
            bf16x8 wf[4], bfr[4];
#pragma unroll
            for (int dt = 0; dt < 4; ++dt)
                wf[dt] = *(const bf16x8*)(wkP + ((size_t)((w * 4 + dt) * 8 + ks)) * 512 + lane * 8);
#pragma unroll
            for (int pt = 0; pt < 4; ++pt)
                bfr[pt] = *(const bf16x8*)(wsiP + (size_t)(((b * 4 + pt) * 8 + ks) * 4 + lg) * 128 + lm * 8);
#pragma unroll
            for (int dt = 0; dt < 4; ++dt)
#pragma unroll
                for (int pt = 0; pt < 4; ++pt)
                    acc[dt * 4 + pt] = __builtin_amdgcn_mfma_f32_16x16x32_bf16(wf[dt], bfr[pt], acc[dt * 4 + pt], 0, 0, 0);
        }
#pragma unroll
        for (int dt = 0; dt < 4; ++dt) {
            int d0 = wd0 + dt * 16 + lg * 4;
            float4 bb = *(const float4*)(bk + d0);
#pragma unroll
            for (int pt = 0; pt < 4; ++pt) {
                int p = pt * 16 + lm;
                f32x4 v = acc[dt * 4 + pt];
                uint2 u;
                u.x = pk2(v[0] + bb.x, v[1] + bb.y);
                u.y = pk2(v[2] + bb.z, v[3] + bb.w);
                int byte = (p * 512 + d0 * 2) ^ ((p & 7) << 4);
                *(uint2*)((char*)kv_s + byte) = u;
            }
        }
    }
    __syncthreads();

    // ---- scores + softmax (wave w -> heads 2w, 2w+1) ----
    float m_reg[2], l_reg[2];
#pragma unroll
    for (int hh = 0; hh < 2; ++hh) {
        int h = w * 2 + hh;
        bf16x8 qf;
        if (lm < 3) qf = *(const bf16x8*)(ub + U_QB + (h * 3 + lm) * 32 + lg * 8);
        else { bf16x8 z = {0,0,0,0,0,0,0,0}; qf = z; }
        f32x4 sc[4];
#pragma unroll
        for (int blk = 0; blk < 4; ++blk) {
            sc[blk] = (f32x4){0.f, 0.f, 0.f, 0.f};
            int p = blk * 16 + lm;
            int byte = (p * 512 + (h * 32 + lg * 8) * 2) ^ ((p & 7) << 4);
            bf16x8 kf = *(const bf16x8*)((const char*)kv_s + byte);
            sc[blk] = __builtin_amdgcn_mfma_f32_16x16x32_bf16(kf, qf, sc[blk], 0, 0, 0);
        }
        float tmax = -INFINITY;
#pragma unroll
        for (int blk = 0; blk < 4; ++blk)
#pragma unroll
            for (int j = 0; j < 4; ++j) {
                int p = blk * 16 + lg * 4 + j;
                if (n0 + p >= 60000) sc[blk][j] = -INFINITY;
                tmax = fmaxf(tmax, sc[blk][j]);
            }
        tmax = fmaxf(tmax, __shfl_xor(tmax, 16));
        tmax = fmaxf(tmax, __shfl_xor(tmax, 32));
        float lsum = 0.f;
#pragma unroll
        for (int blk = 0; blk < 4; ++blk)
#pragma unroll
            for (int j = 0; j < 4; ++j) {
                float e = __expf(sc[blk][j] - tmax);
                sc[blk][j] = e;
                lsum += e;
            }
        lsum += __shfl_xor(lsum, 16);
        lsum += __shfl_xor(lsum, 32);
        m_reg[hh] = tmax;
        l_reg[hh] = lsum;
        if (lm < 3) {
#pragma unroll
            for (int blk = 0; blk < 4; ++blk) {
                int p0 = blk * 16 + lg * 4;
                *(unsigned int*)(p_s + (h * 3 + lm) * 64 + p0) = pk2(sc[blk][0], sc[blk][1]);
                *(unsigned int*)(p_s + (h * 3 + lm) * 64 + p0 + 2) = pk2(sc[blk][2], sc[blk][3]);
            }
        }
    }
    __syncthreads();

    // ---- V projection -> vT (reuse kv_s) ----
    {
        f32x4 acc[16];
#pragma unroll
        for (int i = 0; i < 16; ++i) acc[i] = (f32x4){0.f, 0.f, 0.f, 0.f};
#pragma unroll
        for (int ks = 0; ks < 8; ++ks) {
            bf16x8 wf[4], bfr[4];
#pragma unroll
            for (int dt = 0; dt < 4; ++dt)
                wf[dt] = *(const bf16x8*)(wvP + ((size_t)((w * 4 + dt) * 8 + ks)) * 512 + lane * 8);
#pragma unroll
            for (int pt = 0; pt < 4; ++pt)
                bfr[pt] = *(const bf16x8*)(wsiP + (size_t)(((b * 4 + pt) * 8 + ks) * 4 + lg) * 128 + lm * 8);
#pragma unroll
            for (int dt = 0; dt < 4; ++dt)
#pragma unroll
                for (int pt = 0; pt < 4; ++pt)
                    acc[dt * 4 + pt] = __builtin_amdgcn_mfma_f32_16x16x32_bf16(wf[dt], bfr[pt], acc[dt * 4 + pt], 0, 0, 0);
        }
        __syncthreads();  // all waves done reading kv_s (scores) before overwrite
#pragma unroll
        for (int dt = 0; dt < 4; ++dt) {
            int d0 = wd0 + dt * 16 + lg * 4;
            float4 bb = *(const float4*)(bv + d0);
#pragma unroll
            for (int pt = 0; pt < 4; ++pt) {
                int p = pt * 16 + lm;
                f32x4 v = acc[dt * 4 + pt];
                float r[4] = {v[0] + bb.x, v[1] + bb.y, v[2] + bb.z, v[3] + bb.w};
#pragma unroll
                for (int j = 0; j < 4; ++j) {
                    int dd = d0 + j;
                    int byte = (dd * 128 + p * 2) ^ ((dd & 7) << 4);
                    *(ushort_t*)((char*)kv_s + byte) = f2bf(r[j]);
                }
            }
        }
    }
    __syncthreads();

    // ---- PV (MFMA) ----
    f32x4 pv[2][2];
#pragma unroll
    for (int hh = 0; hh < 2; ++hh)
#pragma unroll
        for (int nb = 0; nb < 2; ++nb) pv[hh][nb] = (f32x4){0.f, 0.f, 0.f, 0.f};
#pragma unroll
    for (int hh = 0; hh < 2; ++hh) {
        int h = w * 2 + hh;
#pragma unroll
        for (int ks = 0; ks < 2; ++ks) {
            bf16x8 pa = *(const bf16x8*)(p_s + (h * 3 + lmc) * 64 + ks * 32 + lg * 8);
#pragma unroll
            for (int nb = 0; nb < 2; ++nb) {
                int row = h * 32 + nb * 16 + lm;
                int byte = (row * 128 + (ks * 32 + lg * 8) * 2) ^ ((row & 7) << 4);
                bf16x8 vb = *(const bf16x8*)((const char*)kv_s + byte);
                pv[hh][nb] = __builtin_amdgcn_mfma_f32_16x16x32_bf16(pa, vb, pv[hh][nb], 0, 0, 0);
            }
        }
    }

    // ---- attention partials ----
    if (lg == 0) {
#pragma unroll
        for (int hh = 0; hh < 2; ++hh)
#pragma unroll
            for (int nb = 0; nb < 2; ++nb)
#pragma unroll
                for (int j = 0; j < 3; ++j) {
                    int hq = (w * 2 + hh) * 3 + j;
                    wsf[WS_PACC + b * 768 + hq * 32 + nb * 16 + lm] = pv[hh][nb][j];
                }
    }
    if (lm < 3 && lg == 0) {
#pragma unroll
        for (int hh = 0; hh < 2; ++hh) {
            int hq = (w * 2 + hh) * 3 + lm;
            wsf[WS_PM + b * 24 + hq] = m_reg[hh];
            wsf[WS_PL + b * 24 + hq] = l_reg[hh];
        }
    }

    // ---- pooling partials (block's wsiP slice, cache-hot) ----
#pragma unroll 1
    for (int it = 0; it < 2; ++it) {
        float pl0[8], pl1[8], pl2[8];
#pragma unroll
        for (int e = 0; e < 8; ++e) { pl0[e] = 0.f; pl1[e] = 0.f; pl2[e] = 0.f; }
        int slot = tid + it * 256;               // [0,512)
        int ks = slot >> 6, lg2 = (slot >> 4) & 3, lm2 = slot & 15;
#pragma unroll
        for (int pt = 0; pt < 4; ++pt) {
            int p16 = b * 4 + pt;
            if (p16 < 3750) {
                uint4 u = *(const uint4*)(wsiP + (size_t)((p16 * 8 + ks) * 4 + lg2) * 128 + lm2 * 8);
                float v0 = bf2f(u.x & 0xffffu), v1 = bf2f(u.x >> 16);
                float v2 = bf2f(u.y & 0xffffu), v3 = bf2f(u.y >> 16);
                float v4 = bf2f(u.z & 0xffffu), v5 = bf2f(u.z >> 16);
                float v6 = bf2f(u.w & 0xffffu), v7 = bf2f(u.w >> 16);
                if (p16 >= 2500) {
                    pl2[0]+=v0; pl2[1]+=v1; pl2[2]+=v2; pl2[3]+=v3;
                    pl2[4]+=v4; pl2[5]+=v5; pl2[6]+=v6; pl2[7]+=v7;
                } else if (p16 >= 1250) {
                    pl1[0]+=v0; pl1[1]+=v1; pl1[2]+=v2; pl1[3]+=v3;
                    pl1[4]+=v4; pl1[5]+=v5; pl1[6]+=v6; pl1[7]+=v7;
                } else {
                    pl0[0]+=v0; pl0[1]+=v1; pl0[2]+=v2; pl0[3]+=v3;
                    pl0[4]+=v4; pl0[5]+=v5; pl0[6]+=v6; pl0[7]+=v7;
                }
            }
        }
#pragma unroll
        for (int o = 1; o < 16; o <<= 1)
#pragma unroll
            for (int e = 0; e < 8; ++e) {
                pl0[e] += __shfl_xor(pl0[e], o);
                pl1[e] += __shfl_xor(pl1[e], o);
                pl2[e] += __shfl_xor(pl2[e], o);
            }
        if (lm2 == 0) {
            int dbase = ks * 32 + lg2 * 8;
#pragma unroll
            for (int e = 0; e < 8; ++e) {
                wsf[WS_PPOOL + b * 768 + 0 * 256 + dbase + e] = pl0[e];
                wsf[WS_PPOOL + b * 768 + 1 * 256 + dbase + e] = pl1[e];
                wsf[WS_PPOOL + b * 768 + 2 * 256 + dbase + e] = pl2[e];
            }
        }
    }
}

// ================== FUSED FALLBACK (round-3 main, proven) ==================
#define LOAD_X(xr, c) { \
    _Pragma("unroll") for (int i_ = 0; i_ < 4; ++i_) { \
        int f_ = tid + i_ * 512; int p_ = f_ >> 4, c4_ = f_ & 15; \
        if (n0 + p_ < 60000) \
            xr[i_] = *(const float4*)(xp + (size_t)(n0 + p_) * 1024 + (c) * 64 + c4_ * 4); \
        else { xr[i_].x = 0.f; xr[i_].y = 0.f; xr[i_].z = 0.f; xr[i_].w = 0.f; } } }

#define STORE_X(xr) { \
    _Pragma("unroll") for (int i_ = 0; i_ < 4; ++i_) { \
        int f_ = tid + i_ * 512; int p_ = f_ >> 4, c4_ = f_ & 15; \
        int byte_ = (p_ * 128 + c4_ * 8) ^ ((p_ & 7) << 4); \
        uint2 u_; u_.x = pk2(xr[i_].x, xr[i_].y); u_.y = pk2(xr[i_].z, xr[i_].w); \
        *(uint2*)((char*)x_s + byte_) = u_; } }

#define LOAD_W1(dst, c) { \
    _Pragma("unroll") for (int ks_ = 0; ks_ < 2; ++ks_) \
    _Pragma("unroll") for (int dt_ = 0; dt_ < 4; ++dt_) \
        dst[ks_ * 4 + dt_] = *(const bf16x8*)(wpP + ((size_t)(((w & 3) * 4 + dt_) * 32 + (c) * 2 + ks_)) * 512 + lane * 8); }

#define MFMA_CHUNK(wf) { \
    _Pragma("unroll") for (int ks_ = 0; ks_ < 2; ++ks_) { \
        bf16x8 bfr_[4]; \
        _Pragma("unroll") for (int pt_ = 0; pt_ < 4; ++pt_) { \
            int p_ = wp0 + pt_ * 16 + lm; \
            int byte_ = (p_ * 128 + ks_ * 64 + lg * 16) ^ ((p_ & 7) << 4); \
            bfr_[pt_] = *(const bf16x8*)((const char*)x_s + byte_); } \
        _Pragma("unroll") for (int dt_ = 0; dt_ < 4; ++dt_) \
        _Pragma("unroll") for (int pt_ = 0; pt_ < 4; ++pt_) \
            acc[dt_ * 4 + pt_] = __builtin_amdgcn_mfma_f32_16x16x32_bf16(wf[ks_ * 4 + dt_], bfr_[pt_], acc[dt_ * 4 + pt_], 0, 0, 0); } }

__global__ __launch_bounds__(512, 2) void main_kernel(
    const float* __restrict__ xp, const float* __restrict__ bp,
    const float* __restrict__ bk, const float* __restrict__ bv,
    const ushort_t* __restrict__ ub, float* __restrict__ wsf)
{
    __shared__ __align__(16) ushort_t wsi_s[128 * 256];
    __shared__ __align__(16) ushort_t kv_s[128 * 256];
    __shared__ __align__(16) ushort_t x_s[128 * 64];
    __shared__ __align__(16) ushort_t p_s[NHQ * 128];
    __shared__ float mlc_s[72];

    const int tid = threadIdx.x;
    const int b = blockIdx.x;
    const int lane = tid & 63;
    const int w = tid >> 6;
    const int lm = lane & 15;
    const int lg = lane >> 4;
    const int lmc = (lm < 3) ? lm : 2;
    const int wd0 = (w & 3) * 64;
    const int wp0 = (w >> 2) * 64;

    const ushort_t* wpP = ub + U_WPT;
    const ushort_t* wkP = ub + U_WKT;
    const ushort_t* wvP = ub + U_WVT;

    bf16x8 qfrag;
    if (lm < 3) qfrag = *(const bf16x8*)(ub + U_QB + (w * 3 + lm) * 32 + lg * 8);
    else { bf16x8 z = {0,0,0,0,0,0,0,0}; qfrag = z; }

    if (tid < 24) { mlc_s[tid] = -INFINITY; mlc_s[24 + tid] = 0.f; mlc_s[48 + tid] = 0.f; }

    f32x4 pv[2] = {{0.f,0.f,0.f,0.f},{0.f,0.f,0.f,0.f}};
    float pl0 = 0.f, pl1 = 0.f, pl2 = 0.f;
    __syncthreads();

    const int n0 = b * 128;
    {
        f32x4 acc[16];
#pragma unroll
        for (int i = 0; i < 16; ++i) acc[i] = (f32x4){0.f,0.f,0.f,0.f};
        float4 xr[4];
        bf16x8 wA[8], wB[8];
        LOAD_X(xr, 0); LOAD_W1(wA, 0);
        for (int c = 0; c < 16; c += 2) {
            __syncthreads();
            STORE_X(xr);
            __syncthreads();
            LOAD_X(xr, c + 1); LOAD_W1(wB, c + 1);
            MFMA_CHUNK(wA);
            __syncthreads();
            STORE_X(xr);
            __syncthreads();
            if (c + 2 < 16) { LOAD_X(xr, c + 2); LOAD_W1(wA, c + 2); }
            MFMA_CHUNK(wB);
        }
#pragma unroll
        for (int dt = 0; dt < 4; ++dt) {
            int d0 = wd0 + dt * 16 + lg * 4;
            float4 bb = *(const float4*)(bp + d0);
#pragma unroll
            for (int pt = 0; pt < 4; ++pt) {
                int p = wp0 + pt * 16 + lm;
                f32x4 v = acc[dt * 4 + pt];
                uint2 u;
                u.x = pk2(fmaxf(v[0] + bb.x, 0.f), fmaxf(v[1] + bb.y, 0.f));
                u.y = pk2(fmaxf(v[2] + bb.z, 0.f), fmaxf(v[3] + bb.w, 0.f));
                int byte = (p * 512 + d0 * 2) ^ ((p & 7) << 4);
                *(uint2*)((char*)wsi_s + byte) = u;
            }
        }
    }
    __syncthreads();

    {
        int d = tid & 255, half = tid >> 8;
#pragma unroll 16
        for (int pp = 0; pp < 64; ++pp) {
            int p = half * 64 + pp;
            int gp = n0 + p;
            int byte = (p * 512 + d * 2) ^ ((p & 7) << 4);
            float v = bf2f((unsigned int)*(const ushort_t*)((const char*)wsi_s + byte));
            pl0 += (gp < 20000) ? v : 0.f;
            pl1 += (gp >= 20000 && gp < 40000) ? v : 0.f;
            pl2 += (gp >= 40000 && gp < 60000) ? v : 0.f;
        }
    }

    {
        f32x4 acc2[16];
#pragma unroll
        for (int i = 0; i < 16; ++i) acc2[i] = (f32x4){0.f,0.f,0.f,0.f};
#pragma unroll
        for (int ks = 0; ks < 8; ++ks) {
            bf16x8 wf[4];
#pragma unroll
            for (int dt = 0; dt < 4; ++dt)
                wf[dt] = *(const bf16x8*)(wkP + ((size_t)(((w & 3) * 4 + dt) * 8 + ks)) * 512 + lane * 8);
            bf16x8 bfr[4];
#pragma unroll
            for (int pt = 0; pt < 4; ++pt) {
                int p = wp0 + pt * 16 + lm;
                int byte = (p * 512 + (ks * 32 + lg * 8) * 2) ^ ((p & 7) << 4);
                bfr[pt] = *(const bf16x8*)((const char*)wsi_s + byte);
            }
#pragma unroll
            for (int dt = 0; dt < 4; ++dt)
#pragma unroll
                for (int pt = 0; pt < 4; ++pt)
                    acc2[dt * 4 + pt] = __builtin_amdgcn_mfma_f32_16x16x32_bf16(wf[dt], bfr[pt], acc2[dt * 4 + pt], 0, 0, 0);
        }
#pragma unroll
        for (int dt = 0; dt < 4; ++dt) {
            int d0 = wd0 + dt * 16 + lg * 4;
            float4 bb = *(const float4*)(bk + d0);
#pragma unroll
            for (int pt = 0; pt < 4; ++pt) {
                int p = wp0 + pt * 16 + lm;
                f32x4 v = acc2[dt * 4 + pt];
                uint2 u;
                u.x = pk2(v[0] + bb.x, v[1] + bb.y);
                u.y = pk2(v[2] + bb.z, v[3] + bb.w);
                int byte = (p * 512 + d0 * 2) ^ ((p & 7) << 4);
                *(uint2*)((char*)kv_s + byte) = u;
            }
        }
    }
    __syncthreads();

    {
        f32x4 sc[8];
#pragma unroll
        for (int blk = 0; blk < 8; ++blk) {
            sc[blk] = (f32x4){0.f,0.f,0.f,0.f};
            int p = blk * 16 + lm;
            int byte = (p * 512 + (w * 32 + lg * 8) * 2) ^ ((p & 7) << 4);
            bf16x8 kf = *(const bf16x8*)((const char*)kv_s + byte);
            sc[blk] = __builtin_amdgcn_mfma_f32_16x16x32_bf16(kf, qfrag, sc[blk], 0, 0, 0);
        }
        float m_old = mlc_s[w * 3 + lmc];
        float tmax = -INFINITY;
#pragma unroll
        for (int blk = 0; blk < 8; ++blk)
#pragma unroll
            for (int j = 0; j < 4; ++j) {
                int p = blk * 16 + lg * 4 + j;
                if (n0 + p >= 60000) sc[blk][j] = -INFINITY;
                tmax = fmaxf(tmax, sc[blk][j]);
            }
        tmax = fmaxf(tmax, __shfl_xor(tmax, 16));
        tmax = fmaxf(tmax, __shfl_xor(tmax, 32));
        float mnew = fmaxf(m_old, tmax);
        float lsum = 0.f;
#pragma unroll
        for (int blk = 0; blk < 8; ++blk)
#pragma unroll
            for (int j = 0; j < 4; ++j) {
                float e = __expf(sc[blk][j] - mnew);
                sc[blk][j] = e;
                lsum += e;
            }
        lsum += __shfl_xor(lsum, 16);
        lsum += __shfl_xor(lsum, 32);
        float corr = __expf(m_old - mnew);
        if (lane < 3) {
            mlc_s[w * 3 + lane] = mnew;
            mlc_s[24 + w * 3 + lane] = mlc_s[24 + w * 3 + lane] * corr + lsum;
            mlc_s[48 + w * 3 + lane] = corr;
        }
        if (lm < 3) {
#pragma unroll
            for (int blk = 0; blk < 8; ++blk) {
                int p0 = blk * 16 + lg * 4;
                *(unsigned int*)(p_s + (w * 3 + lm) * 128 + p0) = pk2(sc[blk][0], sc[blk][1]);
                *(unsigned int*)(p_s + (w * 3 + lm) * 128 + p0 + 2) = pk2(sc[blk][2], sc[blk][3]);
            }
        }
    }
    __syncthreads();

    {
        f32x4 acc2[16];
#pragma unroll
        for (int i = 0; i < 16; ++i) acc2[i] = (f32x4){0.f,0.f,0.f,0.f};
#pragma unroll
        for (int ks = 0; ks < 8; ++ks) {
            bf16x8 wf[4];
#pragma unroll
            for (int dt = 0; dt < 4; ++dt)
                wf[dt] = *(const bf16x8*)(wvP + ((size_t)(((w & 3) * 4 + dt) * 8 + ks)) * 512 + lane * 8);
            bf16x8 bfr[4];
#pragma unroll
            for (int pt = 0; pt < 4; ++pt) {
                int p = wp0 + pt * 16 + lm;
                int byte = (p * 512 + (ks * 32 + lg * 8) * 2) ^ ((p & 7) << 4);
                bfr[pt] = *(const bf16x8*)((const char*)wsi_s + byte);
            }
#pragma unroll
            for (int dt = 0; dt < 4; ++dt)
#pragma unroll
                for (int pt = 0; pt < 4; ++pt)
                    acc2[dt * 4 + pt] = __builtin_amdgcn_mfma_f32_16x16x32_bf16(wf[dt], bfr[pt], acc2[dt * 4 + pt], 0, 0, 0);
        }
#pragma unroll
        for (int dt = 0; dt < 4; ++dt) {
            int d0 = wd0 + dt * 16 + lg * 4;
            float4 bb = *(const float4*)(bv + d0);
#pragma unroll
            for (int pt = 0; pt < 4; ++pt) {
                int p = wp0 + pt * 16 + lm;
                f32x4 v = acc2[dt * 4 + pt];
                float r[4] = {v[0] + bb.x, v[1] + bb.y, v[2] + bb.z, v[3] + bb.w};
#pragma unroll
                for (int j = 0; j < 4; ++j) {
                    int dd = d0 + j;
                    int byte = (dd * 256 + p * 2) ^ ((dd & 14) << 2);
                    *(ushort_t*)((char*)kv_s + byte) = f2bf(r[j]);
                }
            }
        }
    }
    __syncthreads();

    {
        float cj[4];
#pragma unroll
        for (int j = 0; j < 4; ++j) {
            int q = lg * 4 + j;
            cj[j] = mlc_s[48 + w * 3 + (q < 3 ? q : 2)];
        }
#pragma unroll
        for (int nb = 0; nb < 2; ++nb)
#pragma unroll
            for (int j = 0; j < 4; ++j) pv[nb][j] *= cj[j];
#pragma unroll
        for (int ks = 0; ks < 4; ++ks) {
            bf16x8 pa = *(const bf16x8*)(p_s + (w * 3 + lmc) * 128 + ks * 32 + lg * 8);
#pragma unroll
            for (int nb = 0; nb < 2; ++nb) {
                int row = w * 32 + nb * 16 + lm;
                int byte = (row * 256 + (ks * 32 + lg * 8) * 2) ^ ((row & 14) << 2);
                bf16x8 vb = *(const bf16x8*)((const char*)kv_s + byte);
                pv[nb] = __builtin_amdgcn_mfma_f32_16x16x32_bf16(pa, vb, pv[nb], 0, 0, 0);
            }
        }
    }

    __syncthreads();
    {
        float* scr = (float*)x_s;
        int d = tid & 255, half = tid >> 8;
        scr[half * 768 + 0 * 256 + d] = pl0;
        scr[half * 768 + 1 * 256 + d] = pl1;
        scr[half * 768 + 2 * 256 + d] = pl2;
    }
    __syncthreads();
    if (tid < 256) {
        float* scr = (float*)x_s;
#pragma unroll
        for (int bin = 0; bin < 3; ++bin)
            wsf[WS_PPOOL + b * 768 + bin * 256 + tid] = scr[bin * 256 + tid] + scr[768 + bin * 256 + tid];
    }
    if (tid < 24) {
        wsf[WS_PM + b * 24 + tid] = mlc_s[tid];
        wsf[WS_PL + b * 24 + tid] = mlc_s[24 + tid];
    }
    if (lg == 0) {
#pragma unroll
        for (int nb = 0; nb < 2; ++nb)
#pragma unroll
            for (int j = 0; j < 3; ++j) {
                int hq = w * 3 + j, dd = nb * 16 + lm;
                wsf[WS_PACC + b * 768 + hq * 32 + dd] = pv[nb][j];
            }
    }
}

// ---------------- combine partials (parallel) ----------------
__global__ __launch_bounds__(256) void combine_kernel(float* __restrict__ wsf, int nblk, int npool) {
    const int bidx = blockIdx.x;
    const int t = threadIdx.x;
    if (bidx < NHQ) {
        const int hq = bidx;
        __shared__ float w_s[1024];
        __shared__ float mred[4];
        __shared__ float lred[4];
        __shared__ float ored[8][32];
        float m = -INFINITY;
        for (int b = t; b < nblk; b += 256) m = fmaxf(m, wsf[WS_PM + b * 24 + hq]);
#pragma unroll
        for (int o = 32; o > 0; o >>= 1) m = fmaxf(m, __shfl_xor(m, o));
        if ((t & 63) == 0) mred[t >> 6] = m;
        __syncthreads();
        const float M = fmaxf(fmaxf(mred[0], mred[1]), fmaxf(mred[2], mred[3]));
        float L = 0.f;
        for (int b = t; b < nblk; b += 256) {
            float wv = __expf(wsf[WS_PM + b * 24 + hq] - M);
            w_s[b] = wv;
            L += wv * wsf[WS_PL + b * 24 + hq];
        }
#pragma unroll
        for (int o = 32; o > 0; o >>= 1) L += __shfl_xor(L, o);
        if ((t & 63) == 0) lred[t >> 6] = L;
        __syncthreads();
        const float Lt = lred[0] + lred[1] + lred[2] + lred[3];
        const int g = t >> 5, dd = t & 31;
        float O = 0.f;
        for (int b = g; b < nblk; b += 8)
            O += wsf[WS_PACC + b * 768 + hq * 32 + dd] * w_s[b];
        ored[g][dd] = O;
        __syncthreads();
        if (t < 32) {
            float s = 0.f;
#pragma unroll
            for (int g2 = 0; g2 < 8; ++g2) s += ored[g2][t];
            int h = hq / 3, kq = hq - h * 3;
            wsf[WS_ATTN + kq * 256 + h * 32 + t] = s / Lt;
        }
    } else {
        const int bin = bidx - NHQ;
        const int d = t;
        float s0 = 0.f, s1 = 0.f, s2 = 0.f, s3 = 0.f;
        int b = 0;
        for (; b + 3 < npool; b += 4) {
            s0 += wsf[WS_PPOOL + (b + 0) * 768 + bin * 256 + d];
            s1 += wsf[WS_PPOOL + (b + 1) * 768 + bin * 256 + d];
            s2 += wsf[WS_PPOOL + (b + 2) * 768 + bin * 256 + d];
            s3 += wsf[WS_PPOOL + (b + 3) * 768 + bin * 256 + d];
        }
        for (; b < npool; ++b) s0 += wsf[WS_PPOOL + b * 768 + bin * 256 + d];
        wsf[WS_POOLED + bin * 256 + d] = (s0 + s1 + s2 + s3) * (1.f / 20000.f);
    }
}

// ---------------- epilogue ----------------
__device__ __forceinline__ float block_sum256(float v, float* red, int t) {
#pragma unroll
    for (int o = 32; o > 0; o >>= 1) v += __shfl_xor(v, o);
    if ((t & 63) == 0) red[t >> 6] = v;
    __syncthreads();
    float r = red[0] + red[1] + red[2] + red[3];
    __syncthreads();
    return r;
}

__global__ void final_kernel(const float* __restrict__ wo, const float* __restrict__ bo,
                             const float* __restrict__ ln1g, const float* __restrict__ ln1b,
                             const float* __restrict__ wf1, const float* __restrict__ bf1,
                             const float* __restrict__ wf2, const float* __restrict__ bf2,
                             const float* __restrict__ ln2g, const float* __restrict__ ln2b,
                             const float* __restrict__ wc, const float* __restrict__ bc,
                             float* __restrict__ wsf, float* __restrict__ out) {
    __shared__ float attnC[3][256];
    __shared__ float att[3][256];
    __shared__ float amean[256];
    __shared__ float gf[256];
    __shared__ float f1[256];
    __shared__ float red[256];
    const int t = threadIdx.x;
    for (int j = t; j < 768; j += 256) ((float*)attnC)[j] = wsf[WS_ATTN + j];
    gf[t] = wsf[WS_GENE + t];
    __syncthreads();
    for (int kq = 0; kq < 3; ++kq) {
        float acc = bo[t];
        for (int j = 0; j < 256; ++j) acc += attnC[kq][j] * wo[j * 256 + t];
        float x = acc + wsf[WS_POOLED + kq * 256 + t];
        float m = block_sum256(x, red, t) * (1.f / 256.f);
        float dv = x - m;
        float var = block_sum256(dv * dv, red, t) * (1.f / 256.f);
        att[kq][t] = dv * rsqrtf(var + LN_EPS) * ln1g[t] + ln1b[t];
    }
    __syncthreads();
    amean[t] = (att[0][t] + att[1][t] + att[2][t]) * (1.f / 3.f);
    __syncthreads();
    {
        float acc = bf1[t];
        for (int j = 0; j < 256; ++j) acc += amean[j] * wf1[j * 256 + t];
        for (int j = 0; j < 256; ++j) acc += gf[j] * wf1[(256 + j) * 256 + t];
        f1[t] = fmaxf(acc, 0.f);
    }
    __syncthreads();
    float acc2 = bf2[t];
    for (int j = 0; j < 256; ++j) acc2 += f1[j] * wf2[j * 256 + t];
    float y = fmaxf(acc2, 0.f) + amean[t];
    float m2 = block_sum256(y, red, t) * (1.f / 256.f);
    float dv2 = y - m2;
    float v2 = block_sum256(dv2 * dv2, red, t) * (1.f / 256.f);
    float fused = dv2 * rsqrtf(v2 + LN_EPS) * ln2g[t] + ln2b[t];
    red[t] = fused;
    __syncthreads();
    if (t < 4) {
        float o = bc[t];
        for (int j = 0; j < 256; ++j) o += red[j] * wc[j * 4 + t];
        out[t] = o;
    }
}

// ---------------- launcher ----------------
extern "C" void kernel_launch(void* const* d_in, const int* in_sizes, int n_in,
                              void* d_out, int out_size, void* d_ws, size_t ws_size,
                              hipStream_t stream) {
    const float* xp = (const float*)d_in[0];
    PrepArgs pa;
    for (int i = 0; i < 6; ++i) {
        pa.xo[i] = (const float*)d_in[1 + i];
        pa.w1[i] = (const float*)d_in[7 + i];
        pa.sz[i] = in_sizes[1 + i];
    }
    const float* sb1 = (const float*)d_in[13];
    const float* sw2 = (const float*)d_in[14];
    const float* sb2 = (const float*)d_in[15];
    const float* wp  = (const float*)d_in[16];
    const float* bp  = (const float*)d_in[17];
    const float* wa1 = (const float*)d_in[18];
    const float* ba1 = (const float*)d_in[19];
    const float* wa2 = (const float*)d_in[20];
    const float* ba2 = (const float*)d_in[21];
    const float* wq  = (const float*)d_in[22];
    const float* wk  = (const float*)d_in[23];
    const float* wv  = (const float*)d_in[24];
    const float* wo  = (const float*)d_in[25];
    const float* bq  = (const float*)d_in[26];
    const float* bk  = (const float*)d_in[27];
    const float* bv  = (const float*)d_in[28];
    const float* bo  = (const float*)d_in[29];
    const float* ln1g = (const float*)d_in[30];
    const float* ln1b = (const float*)d_in[31];
    const float* wf1 = (const float*)d_in[32];
    const float* bf1 = (const float*)d_in[33];
    const float* wf2 = (const float*)d_in[34];
    const float* bf2 = (const float*)d_in[35];
    const float* ln2g = (const float*)d_in[36];
    const float* ln2b = (const float*)d_in[37];
    const float* wc  = (const float*)d_in[38];
    const float* bc  = (const float*)d_in[39];

    float* wsf = (float*)d_ws;
    float* out = (float*)d_out;
    ushort_t* ub = (ushort_t*)(wsf + WS_BF16);

    prep_kernel<<<dim3(48), dim3(256), 0, stream>>>(wp, wk, wv, ub);
    snn_kernel<<<dim3(6), dim3(256), 0, stream>>>(pa, sb1, sw2, sb2, wsf + WS_BAG);
    select_kernel<<<dim3(1), dim3(256), 0, stream>>>(wa1, ba1, wa2, ba2, wq, bq, wsf, ub);

    if (ws_size >= WS_SPLIT_BYTES) {
        ushort_t* wsiP = ub + U_WSIP;
        proj_kernel<<<dim3(NBLK_P), dim3(256), 0, stream>>>(xp, bp, ub, wsiP);
        attn_kernel<<<dim3(NBLK_P), dim3(256), 0, stream>>>(bk, bv, ub, wsiP, wsf);
        combine_kernel<<<dim3(27), dim3(256), 0, stream>>>(wsf, NBLK_P, NBLK_P);
    } else {
        main_kernel<<<dim3(NBLK_F), dim3(512), 0, stream>>>(xp, bp, bk, bv, ub, wsf);
        combine_kernel<<<dim3(27), dim3(256), 0, stream>>>(wsf, NBLK_F, NBLK_F);
    }
    final_kernel<<<dim3(1), dim3(256), 0, stream>>>(wo, bo, ln1g, ln1b, wf1, bf1, wf2, bf2,
                                                    ln2g, ln2b, wc, bc, wsf, out);
}

// Round 8
// 754.748 us; speedup vs baseline: 1.0213x; 1.0213x over previous
//
#include <hip/hip_runtime.h>
#include <hip/hip_bf16.h>
#include <math.h>

typedef unsigned short ushort_t;
typedef __attribute__((ext_vector_type(8))) short bf16x8;
typedef __attribute__((ext_vector_type(4))) float f32x4;

// ---------------- problem constants ----------------
#define NHQ 24             // 8 heads * 3 queries
#define LN_EPS 1e-5f
#define NBLK_F 469         // fused fallback blocks (128 p each)
#define NBLK_P 938         // proj/attn blocks (64 p each)

// ---------------- workspace layout (float offsets) ----------------
#define WS_BAG 0                        // 1536
#define WS_SEL 1536                     // 768
#define WS_GENE 2304                    // 256
#define WS_PM 3584                      // 1024*24
#define WS_PL 28160                     // 1024*24
#define WS_PACC 52736                   // 1024*768
#define WS_PPOOL 839168                 // 1024*768
#define WS_ATTN 1625600                 // 768
#define WS_POOLED 1626368               // 768
#define WS_BF16 1627136                 // ushort region start (byte ofs %16==0)
// ushort offsets inside bf16 region
#define U_WPT 0                         // wp packed: 16 D16 * 32 K32 * 512
#define U_WKT 262144                    // 16 * 8 * 512
#define U_WVT 327680
#define U_QB  393216                    // 24*32 q bf16 (pre-scaled)
#define U_WSIP 401408                   // wsi packed: 3752 p16 * 4096
#define WS_SPLIT_BYTES 38047744ULL

// ---------------- helpers ----------------
__device__ __forceinline__ ushort_t f2bf(float f) {
    __hip_bfloat16 h = __float2bfloat16(f);
    return *reinterpret_cast<ushort_t*>(&h);
}
__device__ __forceinline__ float bf2f(unsigned int u) {
    union { unsigned int i; float f; } c; c.i = u << 16; return c.f;
}
__device__ __forceinline__ unsigned int pk2(float a, float b) {
    return (unsigned int)f2bf(a) | ((unsigned int)f2bf(b) << 16);
}

// ---------------- prep: weights -> bf16 fragment-packed ----------------
__global__ void prep_kernel(const float* __restrict__ wp, const float* __restrict__ wk,
                            const float* __restrict__ wv, ushort_t* __restrict__ ub) {
    const int b = blockIdx.x, t = threadIdx.x;
    if (b < 16) {
        const int D16 = b;
        for (int i = 0; i < 64; ++i) {
            int f = t + i * 256;
            int K32 = f >> 9, r = f & 511;
            int lg = r >> 7, lm2 = (r >> 3) & 15, e = r & 7;
            int k = K32 * 32 + lg * 8 + e, d = D16 * 16 + lm2;
            ub[U_WPT + D16 * 16384 + f] = f2bf(wp[(size_t)k * 256 + d]);
        }
    } else if (b < 32) {
        const int D16 = b - 16;
        for (int i = 0; i < 16; ++i) {
            int f = t + i * 256;
            int K32 = f >> 9, r = f & 511;
            int lg = r >> 7, lm2 = (r >> 3) & 15, e = r & 7;
            int k = K32 * 32 + lg * 8 + e, d = D16 * 16 + lm2;
            ub[U_WKT + D16 * 4096 + f] = f2bf(wk[(size_t)k * 256 + d]);
        }
    } else {
        const int D16 = b - 32;
        for (int i = 0; i < 16; ++i) {
            int f = t + i * 256;
            int K32 = f >> 9, r = f & 511;
            int lg = r >> 7, lm2 = (r >> 3) & 15, e = r & 7;
            int k = K32 * 32 + lg * 8 + e, d = D16 * 16 + lm2;
            ub[U_WVT + D16 * 4096 + f] = f2bf(wv[(size_t)k * 256 + d]);
        }
    }
}

struct PrepArgs {
    const float* xo[6];
    const float* w1[6];
    int sz[6];
};

// ---------------- per-pathway SNN ----------------
__global__ void snn_kernel(PrepArgs pa, const float* __restrict__ sb1,
                           const float* __restrict__ sw2, const float* __restrict__ sb2,
                           float* __restrict__ bag) {
    __shared__ float xsh[600];
    __shared__ float t1sh[256];
    const int i = blockIdx.x;
    const int t = threadIdx.x;
    const int s = pa.sz[i];
    const float* xo = pa.xo[i];
    const float* w1 = pa.w1[i];
    for (int j = t; j < s; j += 256) xsh[j] = xo[j];
    __syncthreads();
    float acc = sb1[i * 256 + t];
    for (int j = 0; j < s; ++j) acc += xsh[j] * w1[j * 256 + t];
    t1sh[t] = acc > 0.f ? acc : expm1f(acc);
    __syncthreads();
    float acc2 = sb2[i * 256 + t];
    const float* w2 = sw2 + (size_t)i * 256 * 256;
    for (int j = 0; j < 256; ++j) acc2 += t1sh[j] * w2[j * 256 + t];
    bag[i * 256 + t] = acc2 > 0.f ? acc2 : expm1f(acc2);
}

// ---------------- gene scores, top-3 select, q projection (-> bf16) ----------------
__global__ void select_kernel(const float* __restrict__ wa1, const float* __restrict__ ba1,
                              const float* __restrict__ wa2, const float* __restrict__ ba2,
                              const float* __restrict__ wq, const float* __restrict__ bq,
                              float* __restrict__ wsf, ushort_t* __restrict__ ub) {
    __shared__ float bsh[6][256];
    __shared__ float ysh[64];
    __shared__ float ssh[8];
    __shared__ int isel[3];
    const int t = threadIdx.x;
    for (int j = t; j < 1536; j += 256) ((float*)bsh)[j] = wsf[WS_BAG + j];
    __syncthreads();
    for (int i = 0; i < 6; ++i) {
        if (t < 64) {
            float acc = ba1[t];
            for (int j = 0; j < 256; ++j) acc += bsh[i][j] * wa1[j * 64 + t];
            ysh[t] = fmaxf(acc, 0.f) * wa2[t];
        }
        __syncthreads();
        if (t == 0) {
            float sc = ba2[0];
            for (int j = 0; j < 64; ++j) sc += ysh[j];
            ssh[i] = sc;
        }
        __syncthreads();
    }
    if (t == 0) {
        float sc[6];
        for (int i = 0; i < 6; ++i) sc[i] = ssh[i];
        for (int k = 0; k < 3; ++k) {
            int best = 0; float bv = sc[0];
            for (int i = 1; i < 6; ++i) if (sc[i] > bv) { bv = sc[i]; best = i; }
            isel[k] = best;
            sc[best] = -INFINITY;
        }
    }
    __syncthreads();
    float g = 0.f;
    for (int k = 0; k < 3; ++k) {
        float v = bsh[isel[k]][t];
        wsf[WS_SEL + k * 256 + t] = v;
        g += v;
    }
    wsf[WS_GENE + t] = g * (1.f / 3.f);
    for (int kq = 0; kq < 3; ++kq) {
        float acc = bq[t];
        const float* srow = bsh[isel[kq]];
        for (int j = 0; j < 256; ++j) acc += srow[j] * wq[j * 256 + t];
        float v = acc * 0.17677669529663687f;
        int hq = (t >> 5) * 3 + kq, dd = t & 31;
        ub[U_QB + hq * 32 + dd] = f2bf(v);
    }
}

// ================== SPLIT PATH ==================

// ---- proj v3: 938 blocks x 256 thr, 64 patches; x LDS dbuf + weight reg dbuf ----
#define P2LOAD_X(xr, c) { \
    _Pragma("unroll") for (int i_ = 0; i_ < 4; ++i_) { \
        int f_ = tid + i_ * 256; int p_ = f_ >> 4, c4_ = f_ & 15; \
        if (n0 + p_ < 60000) \
            xr[i_] = *(const float4*)(xp + (size_t)(n0 + p_) * 1024 + (c) * 64 + c4_ * 4); \
        else { xr[i_].x = 0.f; xr[i_].y = 0.f; xr[i_].z = 0.f; xr[i_].w = 0.f; } } }

#define P2STORE_X(xr, buf) { \
    _Pragma("unroll") for (int i_ = 0; i_ < 4; ++i_) { \
        int f_ = tid + i_ * 256; int p_ = f_ >> 4, c4_ = f_ & 15; \
        int byte_ = (p_ * 128 + c4_ * 8) ^ ((p_ & 7) << 4); \
        uint2 u_; u_.x = pk2(xr[i_].x, xr[i_].y); u_.y = pk2(xr[i_].z, xr[i_].w); \
        *(uint2*)((buf) + byte_) = u_; } }

#define P2LOAD_W(dst, c, ks) { \
    _Pragma("unroll") for (int dt_ = 0; dt_ < 4; ++dt_) \
        dst[dt_] = *(const bf16x8*)(wpP + ((size_t)((w * 4 + dt_) * 32 + (c) * 2 + (ks))) * 512 + lane * 8); }

#define P2MFMA(wf, cur, ks) { \
    bf16x8 bfr_[4]; \
    _Pragma("unroll") for (int pt_ = 0; pt_ < 4; ++pt_) { \
        int p_ = pt_ * 16 + lm; \
        int byte_ = (p_ * 128 + (ks) * 64 + lg * 16) ^ ((p_ & 7) << 4); \
        bfr_[pt_] = *(const bf16x8*)((cur) + byte_); } \
    _Pragma("unroll") for (int dt_ = 0; dt_ < 4; ++dt_) \
    _Pragma("unroll") for (int pt_ = 0; pt_ < 4; ++pt_) \
        acc[dt_ * 4 + pt_] = __builtin_amdgcn_mfma_f32_16x16x32_bf16(wf[dt_], bfr_[pt_], acc[dt_ * 4 + pt_], 0, 0, 0); }

__global__ __launch_bounds__(256, 3) void proj_kernel(
    const float* __restrict__ xp, const float* __restrict__ bp,
    const ushort_t* __restrict__ ub, ushort_t* __restrict__ wsiP)
{
    __shared__ __align__(16) char xbuf[2][8192];   // 64p x 64k bf16, swz ^((p&7)<<4)
    const int tid = threadIdx.x;
    const int b = blockIdx.x;
    const int lane = tid & 63;
    const int w = tid >> 6;          // wave 0..3 -> d-range w*64
    const int lm = lane & 15;
    const int lg = lane >> 4;
    const int n0 = b * 64;
    const ushort_t* wpP = ub + U_WPT;

    f32x4 acc[16];
#pragma unroll
    for (int i = 0; i < 16; ++i) acc[i] = (f32x4){0.f, 0.f, 0.f, 0.f};

    float4 xr[4];
    bf16x8 wfA[4], wfB[4];
    P2LOAD_X(xr, 0);
    P2STORE_X(xr, xbuf[0]);
    P2LOAD_X(xr, 1);
    P2LOAD_W(wfA, 0, 0);
    __syncthreads();
#pragma unroll 1
    for (int c = 0; c < 16; ++c) {
        const char* cur = xbuf[c & 1];
        if (c < 15) P2STORE_X(xr, xbuf[(c + 1) & 1]);
        if (c < 14) P2LOAD_X(xr, c + 2);
        P2LOAD_W(wfB, c, 1);          // prefetch ks=1 of this chunk
        P2MFMA(wfA, cur, 0);
        if (c < 15) P2LOAD_W(wfA, c + 1, 0);   // prefetch ks=0 of next chunk
        P2MFMA(wfB, cur, 1);
        __syncthreads();
    }
    // epilogue: relu+bias -> packed fragment store
#pragma unroll
    for (int dt = 0; dt < 4; ++dt) {
        int d0 = w * 64 + dt * 16 + lg * 4;
        float4 bb = *(const float4*)(bp + d0);
        int ks2 = d0 >> 5, lg2 = (d0 >> 3) & 3, e0 = d0 & 7;
#pragma unroll
        for (int pt = 0; pt < 4; ++pt) {
            int p16 = b * 4 + pt;
            f32x4 v = acc[dt * 4 + pt];
            uint2 u;
            u.x = pk2(fmaxf(v[0] + bb.x, 0.f), fmaxf(v[1] + bb.y, 0.f));
            u.y = pk2(fmaxf(v[2] + bb.z, 0.f), fmaxf(v[3] + bb.w, 0.f));
            *(uint2*)(wsiP + (size_t)((p16 * 8 + ks2) * 4 + lg2) * 128 + lm * 8 + e0) = u;
        }
    }
}

// ---- attn: k/v proj (pipelined) + single-shot softmax + PV + pool partials ----
#define ALOAD(wf, bf, wt, ks) { \
    _Pragma("unroll") for (int dt_ = 0; dt_ < 4; ++dt_) \
        wf[dt_] = *(const bf16x8*)((wt) + ((size_t)((w * 4 + dt_) * 8 + (ks))) * 512 + lane * 8); \
    _Pragma("unroll") for (int pt_ = 0; pt_ < 4; ++pt_) \
        bf[pt_] = *(const bf16x8*)(wsiP + (size_t)(((b * 4 + pt_) * 8 + (ks)) * 4 + lg) * 128 + lm * 8); }

#define AMFMA(wf, bf) { \
    _Pragma("unroll") for (int dt_ = 0; dt_ < 4; ++dt_) \
    _Pragma("unroll") for (int pt_ = 0; pt_ < 4; ++pt_) \
        acc[dt_ * 4 + pt_] = __builtin_amdgcn_mfma_f32_16x16x32_bf16(wf[dt_], bf[pt_], acc[dt_ * 4 + pt_], 0, 0, 0); }

__global__ __launch_bounds__(256, 3) void attn_kernel(
    const float* __restrict__ bk, const float* __restrict__ bv,
    const ushort_t* __restrict__ ub, const ushort_t* __restrict__ wsiP,
    float* __restrict__ wsf)
{
    __shared__ __align__(16) ushort_t kv_s[64 * 256];   // k [p][d] swz p ; then vT [d][p] swz d
    __shared__ __align__(16) ushort_t p_s[24 * 64];
    const int tid = threadIdx.x;
    const int b = blockIdx.x;
    const int lane = tid & 63, w = tid >> 6;
    const int lm = lane & 15, lg = lane >> 4;
    const int lmc = lm < 3 ? lm : 2;
    const int n0 = b * 64;
    const int wd0 = w * 64;
    const ushort_t* wkP = ub + U_WKT;
    const ushort_t* wvP = ub + U_WVT;

    // ---- K projection (pipelined) ----
    {
        f32x4 acc[16];
#pragma unroll
        for (int i = 0; i < 16; ++i) acc[i] = (f32x4){0.f, 0.f, 0.f, 0.f};
        bf16x8 wfA[4], bfA[4], wfB[4], bfB[4];
        ALOAD(wfA, bfA, wkP, 0);
#pragma unroll
        for (int ks2 = 0; ks2 < 8; ks2 += 2) {
            ALOAD(wfB, bfB, wkP, ks2 + 1);
            AMFMA(wfA, bfA);
            if (ks2 + 2 < 8) ALOAD(wfA, bfA, wkP, ks2 + 2);
            AMFMA(wfB, bfB);
        }
#pragma unroll
        for (int dt = 0; dt < 4; ++dt) {
            int d0 = wd0 + dt * 16 + lg * 4;
            float4 bb = *(const float4*)(bk + d0);
#pragma unroll
            for (int pt = 0; pt < 4; ++pt) {
                int p = pt * 16 + lm;
                f32x4 v = acc[dt * 4 + pt];
                uint2 u;
                u.x = pk2(v[0] + bb.x, v[1] + bb.y);
                u.y = pk2(v[2] + bb.z, v[3] + bb.w);
                int byte = (p * 512 + d0 * 2) ^ ((p & 7) << 4);
                *(uint2*)((char*)kv_s + byte) = u;
            }
        }
    }
    __syncthreads();

    // ---- scores + softmax (wave w -> heads 2w, 2w+1) ----
    float m_reg[2], l_reg[2];
#pragma unroll
    for (int hh = 0; hh < 2; ++hh) {
        int h = w * 2 + hh;
        bf16x8 qf;
        if (lm < 3) qf = *(const bf16x8*)(ub + U_QB + (h * 3 + lm) * 32 + lg * 8);
        else { bf16x8 z = {0,0,0,0,0,0,0,0}; qf = z; }
        f32x4 sc[4];
#pragma unroll
        for (int blk = 0; blk < 4; ++blk) {
            sc[blk] = (f32x4){0.f, 0.f, 0.f, 0.f};
            int p = blk * 16 + lm;
            int byte = (p * 512 + (h * 32 + lg * 8) * 2) ^ ((p & 7) << 4);
            bf16x8 kf = *(const bf16x8*)((const char*)kv_s + byte);
            sc[blk] = __builtin_amdgcn_mfma_f32_16x16x32_bf16(kf, qf, sc[blk], 0, 0, 0);
        }
        float tmax = -INFINITY;
#pragma unroll
        for (int blk = 0; blk < 4; ++blk)
#pragma unroll
            for (int j = 0; j < 4; ++j) {
                int p = blk * 16 + lg * 4 + j;
                if (n0 + p >= 60000) sc[blk][j] = -INFINITY;
                tmax = fmaxf(tmax, sc[blk][j]);
            }
        tmax = fmaxf(tmax, __shfl_xor(tmax, 16));
        tmax = fmaxf(tmax, __shfl_xor(tmax, 32));
        float lsum = 0.f;
#pragma unroll
        for (int blk = 0; blk < 4; ++blk)
#pragma unroll
            for (int j = 0; j < 4; ++j) {
                float e = __expf(sc[blk][j] - tmax);
                sc[blk][j] = e;
                lsum += e;
            }
        lsum += __shfl_xor(lsum, 16);
        lsum += __shfl_xor(lsum, 32);
        m_reg[hh] = tmax;
        l_reg[hh] = lsum;
        if (lm < 3) {
#pragma unroll
            for (int blk = 0; blk < 4; ++blk) {
                int p0 = blk * 16 + lg * 4;
                *(unsigned int*)(p_s + (h * 3 + lm) * 64 + p0) = pk2(sc[blk][0], sc[blk][1]);
                *(unsigned int*)(p_s + (h * 3 + lm) * 64 + p0 + 2) = pk2(sc[blk][2], sc[blk][3]);
            }
        }
    }
    __syncthreads();

    // ---- V projection -> vT (pipelined, reuse kv_s) ----
    {
        f32x4 acc[16];
#pragma unroll
        for (int i = 0; i < 16; ++i) acc[i] = (f32x4){0.f, 0.f, 0.f, 0.f};
        bf16x8 wfA[4], bfA[4], wfB[4], bfB[4];
        ALOAD(wfA, bfA, wvP, 0);
#pragma unroll
        for (int ks2 = 0; ks2 < 8; ks2 += 2) {
            ALOAD(wfB, bfB, wvP, ks2 + 1);
            AMFMA(wfA, bfA);
            if (ks2 + 2 < 8) ALOAD(wfA, bfA, wvP, ks2 + 2);
            AMFMA(wfB, bfB);
        }
        __syncthreads();  // all waves done reading kv_s (scores) before overwrite
#pragma unroll
        for (int dt = 0; dt < 4; ++dt) {
            int d0 = wd0 + dt * 16 + lg * 4;
            float4 bb = *(const float4*)(bv + d0);
#pragma unroll
            for (int pt = 0; pt < 4; ++pt) {
                int p = pt * 16 + lm;
                f32x4 v = acc[dt * 4 + pt];
                float r[4] = {v[0] + bb.x, v[1] + bb.y, v[2] + bb.z, v[3] + bb.w};
#pragma unroll
                for (int j = 0; j < 4; ++j) {
                    int dd = d0 + j;
                    int byte = (dd * 128 + p * 2) ^ ((dd & 7) << 4);
                    *(ushort_t*)((char*)kv_s + byte) = f2bf(r[j]);
                }
            }
        }
    }
    __syncthreads();

    // ---- PV (MFMA) ----
    f32x4 pv[2][2];
#pragma unroll
    for (int hh = 0; hh < 2; ++hh)
#pragma unroll
        for (int nb = 0; nb < 2; ++nb) pv[hh][nb] = (f32x4){0.f, 0.f, 0.f, 0.f};
#pragma unroll
    for (int hh = 0; hh < 2; ++hh) {
        int h = w * 2 + hh;
#pragma unroll
        for (int ks = 0; ks < 2; ++ks) {
            bf16x8 pa = *(const bf16x8*)(p_s + (h * 3 + lmc) * 64 + ks * 32 + lg * 8);
#pragma unroll
            for (int nb = 0; nb < 2; ++nb) {
                int row = h * 32 + nb * 16 + lm;
                int byte = (row * 128 + (ks * 32 + lg * 8) * 2) ^ ((row & 7) << 4);
                bf16x8 vb = *(const bf16x8*)((const char*)kv_s + byte);
                pv[hh][nb] = __builtin_amdgcn_mfma_f32_16x16x32_bf16(pa, vb, pv[hh][nb], 0, 0, 0);
            }
        }
    }

    // ---- attention partials ----
    if (lg == 0) {
#pragma unroll
        for (int hh = 0; hh < 2; ++hh)
#pragma unroll
            for (int nb = 0; nb < 2; ++nb)
#pragma unroll
                for (int j = 0; j < 3; ++j) {
                    int hq = (w * 2 + hh) * 3 + j;
                    wsf[WS_PACC + b * 768 + hq * 32 + nb * 16 + lm] = pv[hh][nb][j];
                }
    }
    if (lm < 3 && lg == 0) {
#pragma unroll
        for (int hh = 0; hh < 2; ++hh) {
            int hq = (w * 2 + hh) * 3 + lm;
            wsf[WS_PM + b * 24 + hq] = m_reg[hh];
            wsf[WS_PL + b * 24 + hq] = l_reg[hh];
        }
    }

    // ---- pooling partials (block's wsiP slice, cache-hot) ----
#pragma unroll 1
    for (int it = 0; it < 2; ++it) {
        float pl0[8], pl1[8], pl2[8];
#pragma unroll
        for (int e = 0; e < 8; ++e) { pl0[e] = 0.f; pl1[e] = 0.f; pl2[e] = 0.f; }
        int slot = tid + it * 256;               // [0,512)
        int ks = slot >> 6, lg2 = (slot >> 4) & 3, lm2 = slot & 15;
#pragma unroll
        for (int pt = 0; pt < 4; ++pt) {
            int p16 = b * 4 + pt;
            if (p16 < 3750) {
                uint4 u = *(const uint4*)(wsiP + (size_t)((p16 * 8 + ks) * 4 + lg2) * 128 + lm2 * 8);
                float v0 = bf2f(u.x & 0xffffu), v1 = bf2f(u.x >> 16);
                float v2 = bf2f(u.y & 0xffffu), v3 = bf2f(u.y >> 16);
                float v4 = bf2f(u.z & 0xffffu), v5 = bf2f(u.z >> 16);
                float v6 = bf2f(u.w & 0xffffu), v7 = bf2f(u.w >> 16);
                if (p16 >= 2500) {
                    pl2[0]+=v0; pl2[1]+=v1; pl2[2]+=v2; pl2[3]+=v3;
                    pl2[4]+=v4; pl2[5]+=v5; pl2[6]+=v6; pl2[7]+=v7;
                } else if (p16 >= 1250) {
                    pl1[0]+=v0; pl1[1]+=v1; pl1[2]+=v2; pl1[3]+=v3;
                    pl1[4]+=v4; pl1[5]+=v5; pl1[6]+=v6; pl1[7]+=v7;
                } else {
                    pl0[0]+=v0; pl0[1]+=v1; pl0[2]+=v2; pl0[3]+=v3;
                    pl0[4]+=v4; pl0[5]+=v5; pl0[6]+=v6; pl0[7]+=v7;
                }
            }
        }
#pragma unroll
        for (int o = 1; o < 16; o <<= 1)
#pragma unroll
            for (int e = 0; e < 8; ++e) {
                pl0[e] += __shfl_xor(pl0[e], o);
                pl1[e] += __shfl_xor(pl1[e], o);
                pl2[e] += __shfl_xor(pl2[e], o);
            }
        if (lm2 == 0) {
            int dbase = ks * 32 + lg2 * 8;
#pragma unroll
            for (int e = 0; e < 8; ++e) {
                wsf[WS_PPOOL + b * 768 + 0 * 256 + dbase + e] = pl0[e];
                wsf[WS_PPOOL + b * 768 + 1 * 256 + dbase + e] = pl1[e];
                wsf[WS_PPOOL + b * 768 + 2 * 256 + dbase + e] = pl2[e];
            }
        }
    }
}

// ================== FUSED FALLBACK (round-3 main, proven) ==================
#define LOAD_X(xr, c) { \
    _Pragma("unroll") for (int i_ = 0; i_ < 4; ++i_) { \
        int f_ = tid + i_ * 512; int p_ = f_ >> 4, c4_ = f_ & 15; \
        if (n0 + p_ < 60000) \
            xr[i_] = *(const float4*)(xp + (size_t)(n0 + p_) * 1024 + (c) * 64 + c4_ * 4); \
        else { xr[i_].x = 0.f; xr[i_].y = 0.f; xr[i_].z = 0.f; xr[i_].w = 0.f; } } }

#define STORE_X(xr) { \
    _Pragma("unroll") for (int i_ = 0; i_ < 4; ++i_) { \
        int f_ = tid + i_ * 512; int p_ = f_ >> 4, c4_ = f_ & 15; \
        int byte_ = (p_ * 128 + c4_ * 8) ^ ((p_ & 7) << 4); \
        uint2 u_; u_.x = pk2(xr[i_].x, xr[i_].y); u_.y = pk2(xr[i_].z, xr[i_].w); \
        *(uint2*)((char*)x_s + byte_) = u_; } }

#define LOAD_W1(dst, c) { \
    _Pragma("unroll") for (int ks_ = 0; ks_ < 2; ++ks_) \
    _Pragma("unroll") for (int dt_ = 0; dt_ < 4; ++dt_) \
        dst[ks_ * 4 + dt_] = *(const bf16x8*)(wpP + ((size_t)(((w & 3) * 4 + dt_) * 32 + (c) * 2 + ks_)) * 512 + lane * 8); }

#define MFMA_CHUNK(wf) { \
    _Pragma("unroll") for (int ks_ = 0; ks_ < 2; ++ks_) { \
        bf16x8 bfr_[4]; \
        _Pragma("unroll") for (int pt_ = 0; pt_ < 4; ++pt_) { \
            int p_ = wp0 + pt_ * 16 + lm; \
            int byte_ = (p_ * 128 + ks_ * 64 + lg * 16) ^ ((p_ & 7) << 4); \
            bfr_[pt_] = *(const bf16x8*)((const char*)x_s + byte_); } \
        _Pragma("unroll") for (int dt_ = 0; dt_ < 4; ++dt_) \
        _Pragma("unroll") for (int pt_ = 0; pt_ < 4; ++pt_) \
            acc[dt_ * 4 + pt_] = __builtin_amdgcn_mfma_f32_16x16x32_bf16(wf[ks_ * 4 + dt_], bfr_[pt_], acc[dt_ * 4 + pt_], 0, 0, 0); } }

__global__ __launch_bounds__(512, 2) void main_kernel(
    const float* __restrict__ xp, const float* __restrict__ bp,
    const float* __restrict__ bk, const float* __restrict__ bv,
    const ushort_t* __restrict__ ub, float* __restrict__ wsf)
{
    __shared__ __align__(16) ushort_t wsi_s[128 * 256];
    __shared__ __align__(16) ushort_t kv_s[128 * 256];
    __shared__ __align__(16) ushort_t x_s[128 * 64];
    __shared__ __align__(16) ushort_t p_s[NHQ * 128];
    __shared__ float mlc_s[72];

    const int tid = threadIdx.x;
    const int b = blockIdx.x;
    const int lane = tid & 63;
    const int w = tid >> 6;
    const int lm = lane & 15;
    const int lg = lane >> 4;
    const int lmc = (lm < 3) ? lm : 2;
    const int wd0 = (w & 3) * 64;
    const int wp0 = (w >> 2) * 64;

    const ushort_t* wpP = ub + U_WPT;
    const ushort_t* wkP = ub + U_WKT;
    const ushort_t* wvP = ub + U_WVT;

    bf16x8 qfrag;
    if (lm < 3) qfrag = *(const bf16x8*)(ub + U_QB + (w * 3 + lm) * 32 + lg * 8);
    else { bf16x8 z = {0,0,0,0,0,0,0,0}; qfrag = z; }

    if (tid < 24) { mlc_s[tid] = -INFINITY; mlc_s[24 + tid] = 0.f; mlc_s[48 + tid] = 0.f; }

    f32x4 pv[2] = {{0.f,0.f,0.f,0.f},{0.f,0.f,0.f,0.f}};
    float pl0 = 0.f, pl1 = 0.f, pl2 = 0.f;
    __syncthreads();

    const int n0 = b * 128;
    {
        f32x4 acc[16];
#pragma unroll
        for (int i = 0; i < 16; ++i) acc[i] = (f32x4){0.f,0.f,0.f,0.f};
        float4 xr[4];
        bf16x8 wA[8], wB[8];
        LOAD_X(xr, 0); LOAD_W1(wA, 0);
        for (int c = 0; c < 16; c += 2) {
            __syncthreads();
            STORE_X(xr);
            __syncthreads();
            LOAD_X(xr, c + 1); LOAD_W1(wB, c + 1);
            MFMA_CHUNK(wA);
            __syncthreads();
            STORE_X(xr);
            __syncthreads();
            if (c + 2 < 16) { LOAD_X(xr, c + 2); LOAD_W1(wA, c + 2); }
            MFMA_CHUNK(wB);
        }
#pragma unroll
        for (int dt = 0; dt < 4; ++dt) {
            int d0 = wd0 + dt * 16 + lg * 4;
            float4 bb = *(const float4*)(bp + d0);
#pragma unroll
            for (int pt = 0; pt < 4; ++pt) {
                int p = wp0 + pt * 16 + lm;
                f32x4 v = acc[dt * 4 + pt];
                uint2 u;
                u.x = pk2(fmaxf(v[0] + bb.x, 0.f), fmaxf(v[1] + bb.y, 0.f));
                u.y = pk2(fmaxf(v[2] + bb.z, 0.f), fmaxf(v[3] + bb.w, 0.f));
                int byte = (p * 512 + d0 * 2) ^ ((p & 7) << 4);
                *(uint2*)((char*)wsi_s + byte) = u;
            }
        }
    }
    __syncthreads();

    {
        int d = tid & 255, half = tid >> 8;
#pragma unroll 16
        for (int pp = 0; pp < 64; ++pp) {
            int p = half * 64 + pp;
            int gp = n0 + p;
            int byte = (p * 512 + d * 2) ^ ((p & 7) << 4);
            float v = bf2f((unsigned int)*(const ushort_t*)((const char*)wsi_s + byte));
            pl0 += (gp < 20000) ? v : 0.f;
            pl1 += (gp >= 20000 && gp < 40000) ? v : 0.f;
            pl2 += (gp >= 40000 && gp < 60000) ? v : 0.f;
        }
    }

    {
        f32x4 acc2[16];
#pragma unroll
        for (int i = 0; i < 16; ++i) acc2[i] = (f32x4){0.f,0.f,0.f,0.f};
#pragma unroll
        for (int ks = 0; ks < 8; ++ks) {
            bf16x8 wf[4];
#pragma unroll
            for (int dt = 0; dt < 4; ++dt)
                wf[dt] = *(const bf16x8*)(wkP + ((size_t)(((w & 3) * 4 + dt) * 8 + ks)) * 512 + lane * 8);
            bf16x8 bfr[4];
#pragma unroll
            for (int pt = 0; pt < 4; ++pt) {
                int p = wp0 + pt * 16 + lm;
                int byte = (p * 512 + (ks * 32 + lg * 8) * 2) ^ ((p & 7) << 4);
                bfr[pt] = *(const bf16x8*)((const char*)wsi_s + byte);
            }
#pragma unroll
            for (int dt = 0; dt < 4; ++dt)
#pragma unroll
                for (int pt = 0; pt < 4; ++pt)
                    acc2[dt * 4 + pt] = __builtin_amdgcn_mfma_f32_16x16x32_bf16(wf[dt], bfr[pt], acc2[dt * 4 + pt], 0, 0, 0);
        }
#pragma unroll
        for (int dt = 0; dt < 4; ++dt) {
            int d0 = wd0 + dt * 16 + lg * 4;
            float4 bb = *(const float4*)(bk + d0);
#pragma unroll
            for (int pt = 0; pt < 4; ++pt) {
                int p = wp0 + pt * 16 + lm;
                f32x4 v = acc2[dt * 4 + pt];
                uint2 u;
                u.x = pk2(v[0] + bb.x, v[1] + bb.y);
                u.y = pk2(v[2] + bb.z, v[3] + bb.w);
                int byte = (p * 512 + d0 * 2) ^ ((p & 7) << 4);
                *(uint2*)((char*)kv_s + byte) = u;
            }
        }
    }
    __syncthreads();

    {
        f32x4 sc[8];
#pragma unroll
        for (int blk = 0; blk < 8; ++blk) {
            sc[blk] = (f32x4){0.f,0.f,0.f,0.f};
            int p = blk * 16 + lm;
            int byte = (p * 512 + (w * 32 + lg * 8) * 2) ^ ((p & 7) << 4);
            bf16x8 kf = *(const bf16x8*)((const char*)kv_s + byte);
            sc[blk] = __builtin_amdgcn_mfma_f32_16x16x32_bf16(kf, qfrag, sc[blk], 0, 0, 0);
        }
        float m_old = mlc_s[w * 3 + lmc];
        float tmax = -INFINITY;
#pragma unroll
        for (int blk = 0; blk < 8; ++blk)
#pragma unroll
            for (int j = 0; j < 4; ++j) {
                int p = blk * 16 + lg * 4 + j;
                if (n0 + p >= 60000) sc[blk][j] = -INFINITY;
                tmax = fmaxf(tmax, sc[blk][j]);
            }
        tmax = fmaxf(tmax, __shfl_xor(tmax, 16));
        tmax = fmaxf(tmax, __shfl_xor(tmax, 32));
        float mnew = fmaxf(m_old, tmax);
        float lsum = 0.f;
#pragma unroll
        for (int blk = 0; blk < 8; ++blk)
#pragma unroll
            for (int j = 0; j < 4; ++j) {
                float e = __expf(sc[blk][j] - mnew);
                sc[blk][j] = e;
                lsum += e;
            }
        lsum += __shfl_xor(lsum, 16);
        lsum += __shfl_xor(lsum, 32);
        float corr = __expf(m_old - mnew);
        if (lane < 3) {
            mlc_s[w * 3 + lane] = mnew;
            mlc_s[24 + w * 3 + lane] = mlc_s[24 + w * 3 + lane] * corr + lsum;
            mlc_s[48 + w * 3 + lane] = corr;
        }
        if (lm < 3) {
#pragma unroll
            for (int blk = 0; blk < 8; ++blk) {
                int p0 = blk * 16 + lg * 4;
                *(unsigned int*)(p_s + (w * 3 + lm) * 128 + p0) = pk2(sc[blk][0], sc[blk][1]);
                *(unsigned int*)(p_s + (w * 3 + lm) * 128 + p0 + 2) = pk2(sc[blk][2], sc[blk][3]);
            }
        }
    }
    __syncthreads();

    {
        f32x4 acc2[16];
#pragma unroll
        for (int i = 0; i < 16; ++i) acc2[i] = (f32x4){0.f,0.f,0.f,0.f};
#pragma unroll
        for (int ks = 0; ks < 8; ++ks) {
            bf16x8 wf[4];
#pragma unroll
            for (int dt = 0; dt < 4; ++dt)
                wf[dt] = *(const bf16x8*)(wvP + ((size_t)(((w & 3) * 4 + dt) * 8 + ks)) * 512 + lane * 8);
            bf16x8 bfr[4];
#pragma unroll
            for (int pt = 0; pt < 4; ++pt) {
                int p = wp0 + pt * 16 + lm;
                int byte = (p * 512 + (ks * 32 + lg * 8) * 2) ^ ((p & 7) << 4);
                bfr[pt] = *(const bf16x8*)((const char*)wsi_s + byte);
            }
#pragma unroll
            for (int dt = 0; dt < 4; ++dt)
#pragma unroll
                for (int pt = 0; pt < 4; ++pt)
                    acc2[dt * 4 + pt] = __builtin_amdgcn_mfma_f32_16x16x32_bf16(wf[dt], bfr[pt], acc2[dt * 4 + pt], 0, 0, 0);
        }
#pragma unroll
        for (int dt = 0; dt < 4; ++dt) {
            int d0 = wd0 + dt * 16 + lg * 4;
            float4 bb = *(const float4*)(bv + d0);
#pragma unroll
            for (int pt = 0; pt < 4; ++pt) {
                int p = wp0 + pt * 16 + lm;
                f32x4 v = acc2[dt * 4 + pt];
                float r[4] = {v[0] + bb.x, v[1] + bb.y, v[2] + bb.z, v[3] + bb.w};
#pragma unroll
                for (int j = 0; j < 4; ++j) {
                    int dd = d0 + j;
                    int byte = (dd * 256 + p * 2) ^ ((dd & 14) << 2);
                    *(ushort_t*)((char*)kv_s + byte) = f2bf(r[j]);
                }
            }
        }
    }
    __syncthreads();

    {
        float cj[4];
#pragma unroll
        for (int j = 0; j < 4; ++j) {
            int q = lg * 4 + j;
            cj[j] = mlc_s[48 + w * 3 + (q < 3 ? q : 2)];
        }
#pragma unroll
        for (int nb = 0; nb < 2; ++nb)
#pragma unroll
            for (int j = 0; j < 4; ++j) pv[nb][j] *= cj[j];
#pragma unroll
        for (int ks = 0; ks < 4; ++ks) {
            bf16x8 pa = *(const bf16x8*)(p_s + (w * 3 + lmc) * 128 + ks * 32 + lg * 8);
#pragma unroll
            for (int nb = 0; nb < 2; ++nb) {
                int row = w * 32 + nb * 16 + lm;
                int byte = (row * 256 + (ks * 32 + lg * 8) * 2) ^ ((row & 14) << 2);
                bf16x8 vb = *(const bf16x8*)((const char*)kv_s + byte);
                pv[nb] = __builtin_amdgcn_mfma_f32_16x16x32_bf16(pa, vb, pv[nb], 0, 0, 0);
            }
        }
    }

    __syncthreads();
    {
        float* scr = (float*)x_s;
        int d = tid & 255, half = tid >> 8;
        scr[half * 768 + 0 * 256 + d] = pl0;
        scr[half * 768 + 1 * 256 + d] = pl1;
        scr[half * 768 + 2 * 256 + d] = pl2;
    }
    __syncthreads();
    if (tid < 256) {
        float* scr = (float*)x_s;
#pragma unroll
        for (int bin = 0; bin < 3; ++bin)
            wsf[WS_PPOOL + b * 768 + bin * 256 + tid] = scr[bin * 256 + tid] + scr[768 + bin * 256 + tid];
    }
    if (tid < 24) {
        wsf[WS_PM + b * 24 + tid] = mlc_s[tid];
        wsf[WS_PL + b * 24 + tid] = mlc_s[24 + tid];
    }
    if (lg == 0) {
#pragma unroll
        for (int nb = 0; nb < 2; ++nb)
#pragma unroll
            for (int j = 0; j < 3; ++j) {
                int hq = w * 3 + j, dd = nb * 16 + lm;
                wsf[WS_PACC + b * 768 + hq * 32 + dd] = pv[nb][j];
            }
    }
}

// ---------------- combine partials (parallel) ----------------
__global__ __launch_bounds__(256) void combine_kernel(float* __restrict__ wsf, int nblk, int npool) {
    const int bidx = blockIdx.x;
    const int t = threadIdx.x;
    if (bidx < NHQ) {
        const int hq = bidx;
        __shared__ float w_s[1024];
        __shared__ float mred[4];
        __shared__ float lred[4];
        __shared__ float ored[8][32];
        float m = -INFINITY;
        for (int b = t; b < nblk; b += 256) m = fmaxf(m, wsf[WS_PM + b * 24 + hq]);
#pragma unroll
        for (int o = 32; o > 0; o >>= 1) m = fmaxf(m, __shfl_xor(m, o));
        if ((t & 63) == 0) mred[t >> 6] = m;
        __syncthreads();
        const float M = fmaxf(fmaxf(mred[0], mred[1]), fmaxf(mred[2], mred[3]));
        float L = 0.f;
        for (int b = t; b < nblk; b += 256) {
            float wv = __expf(wsf[WS_PM + b * 24 + hq] - M);
            w_s[b] = wv;
            L += wv * wsf[WS_PL + b * 24 + hq];
        }
#pragma unroll
        for (int o = 32; o > 0; o >>= 1) L += __shfl_xor(L, o);
        if ((t & 63) == 0) lred[t >> 6] = L;
        __syncthreads();
        const float Lt = lred[0] + lred[1] + lred[2] + lred[3];
        const int g = t >> 5, dd = t & 31;
        float O = 0.f;
        for (int b = g; b < nblk; b += 8)
            O += wsf[WS_PACC + b * 768 + hq * 32 + dd] * w_s[b];
        ored[g][dd] = O;
        __syncthreads();
        if (t < 32) {
            float s = 0.f;
#pragma unroll
            for (int g2 = 0; g2 < 8; ++g2) s += ored[g2][t];
            int h = hq / 3, kq = hq - h * 3;
            wsf[WS_ATTN + kq * 256 + h * 32 + t] = s / Lt;
        }
    } else {
        const int bin = bidx - NHQ;
        const int d = t;
        float s0 = 0.f, s1 = 0.f, s2 = 0.f, s3 = 0.f;
        int b = 0;
        for (; b + 3 < npool; b += 4) {
            s0 += wsf[WS_PPOOL + (b + 0) * 768 + bin * 256 + d];
            s1 += wsf[WS_PPOOL + (b + 1) * 768 + bin * 256 + d];
            s2 += wsf[WS_PPOOL + (b + 2) * 768 + bin * 256 + d];
            s3 += wsf[WS_PPOOL + (b + 3) * 768 + bin * 256 + d];
        }
        for (; b < npool; ++b) s0 += wsf[WS_PPOOL + b * 768 + bin * 256 + d];
        wsf[WS_POOLED + bin * 256 + d] = (s0 + s1 + s2 + s3) * (1.f / 20000.f);
    }
}

// ---------------- epilogue ----------------
__device__ __forceinline__ float block_sum256(float v, float* red, int t) {
#pragma unroll
    for (int o = 32; o > 0; o >>= 1) v += __shfl_xor(v, o);
    if ((t & 63) == 0) red[t >> 6] = v;
    __syncthreads();
    float r = red[0] + red[1] + red[2] + red[3];
    __syncthreads();
    return r;
}

__global__ void final_kernel(const float* __restrict__ wo, const float* __restrict__ bo,
                             const float* __restrict__ ln1g, const float* __restrict__ ln1b,
                             const float* __restrict__ wf1, const float* __restrict__ bf1,
                             const float* __restrict__ wf2, const float* __restrict__ bf2,
                             const float* __restrict__ ln2g, const float* __restrict__ ln2b,
                             const float* __restrict__ wc, const float* __restrict__ bc,
                             float* __restrict__ wsf, float* __restrict__ out) {
    __shared__ float attnC[3][256];
    __shared__ float att[3][256];
    __shared__ float amean[256];
    __shared__ float gf[256];
    __shared__ float f1[256];
    __shared__ float red[256];
    const int t = threadIdx.x;
    for (int j = t; j < 768; j += 256) ((float*)attnC)[j] = wsf[WS_ATTN + j];
    gf[t] = wsf[WS_GENE + t];
    __syncthreads();
    for (int kq = 0; kq < 3; ++kq) {
        float acc = bo[t];
        for (int j = 0; j < 256; ++j) acc += attnC[kq][j] * wo[j * 256 + t];
        float x = acc + wsf[WS_POOLED + kq * 256 + t];
        float m = block_sum256(x, red, t) * (1.f / 256.f);
        float dv = x - m;
        float var = block_sum256(dv * dv, red, t) * (1.f / 256.f);
        att[kq][t] = dv * rsqrtf(var + LN_EPS) * ln1g[t] + ln1b[t];
    }
    __syncthreads();
    amean[t] = (att[0][t] + att[1][t] + att[2][t]) * (1.f / 3.f);
    __syncthreads();
    {
        float acc = bf1[t];
        for (int j = 0; j < 256; ++j) acc += amean[j] * wf1[j * 256 + t];
        for (int j = 0; j < 256; ++j) acc += gf[j] * wf1[(256 + j) * 256 + t];
        f1[t] = fmaxf(acc, 0.f);
    }
    __syncthreads();
    float acc2 = bf2[t];
    for (int j = 0; j < 256; ++j) acc2 += f1[j] * wf2[j * 256 + t];
    float y = fmaxf(acc2, 0.f) + amean[t];
    float m2 = block_sum256(y, red, t) * (1.f / 256.f);
    float dv2 = y - m2;
    float v2 = block_sum256(dv2 * dv2, red, t) * (1.f / 256.f);
    float fused = dv2 * rsqrtf(v2 + LN_EPS) * ln2g[t] + ln2b[t];
    red[t] = fused;
    __syncthreads();
    if (t < 4) {
        float o = bc[t];
        for (int j = 0; j < 256; ++j) o += red[j] * wc[j * 4 + t];
        out[t] = o;
    }
}

// ---------------- launcher ----------------
extern "C" void kernel_launch(void* const* d_in, const int* in_sizes, int n_in,
                              void* d_out, int out_size, void* d_ws, size_t ws_size,
                              hipStream_t stream) {
    const float* xp = (const float*)d_in[0];
    PrepArgs pa;
    for (int i = 0; i < 6; ++i) {
        pa.xo[i] = (const float*)d_in[1 + i];
        pa.w1[i] = (const float*)d_in[7 + i];
        pa.sz[i] = in_sizes[1 + i];
    }
    const float* sb1 = (const float*)d_in[13];
    const float* sw2 = (const float*)d_in[14];
    const float* sb2 = (const float*)d_in[15];
    const float* wp  = (const float*)d_in[16];
    const float* bp  = (const float*)d_in[17];
    const float* wa1 = (const float*)d_in[18];
    const float* ba1 = (const float*)d_in[19];
    const float* wa2 = (const float*)d_in[20];
    const float* ba2 = (const float*)d_in[21];
    const float* wq  = (const float*)d_in[22];
    const float* wk  = (const float*)d_in[23];
    const float* wv  = (const float*)d_in[24];
    const float* wo  = (const float*)d_in[25];
    const float* bq  = (const float*)d_in[26];
    const float* bk  = (const float*)d_in[27];
    const float* bv  = (const float*)d_in[28];
    const float* bo  = (const float*)d_in[29];
    const float* ln1g = (const float*)d_in[30];
    const float* ln1b = (const float*)d_in[31];
    const float* wf1 = (const float*)d_in[32];
    const float* bf1 = (const float*)d_in[33];
    const float* wf2 = (const float*)d_in[34];
    const float* bf2 = (const float*)d_in[35];
    const float* ln2g = (const float*)d_in[36];
    const float* ln2b = (const float*)d_in[37];
    const float* wc  = (const float*)d_in[38];
    const float* bc  = (const float*)d_in[39];

    float* wsf = (float*)d_ws;
    float* out = (float*)d_out;
    ushort_t* ub = (ushort_t*)(wsf + WS_BF16);

    prep_kernel<<<dim3(48), dim3(256), 0, stream>>>(wp, wk, wv, ub);
    snn_kernel<<<dim3(6), dim3(256), 0, stream>>>(pa, sb1, sw2, sb2, wsf + WS_BAG);
    select_kernel<<<dim3(1), dim3(256), 0, stream>>>(wa1, ba1, wa2, ba2, wq, bq, wsf, ub);

    if (ws_size >= WS_SPLIT_BYTES) {
        ushort_t* wsiP = ub + U_WSIP;
        proj_kernel<<<dim3(NBLK_P), dim3(256), 0, stream>>>(xp, bp, ub, wsiP);
        attn_kernel<<<dim3(NBLK_P), dim3(256), 0, stream>>>(bk, bv, ub, wsiP, wsf);
        combine_kernel<<<dim3(27), dim3(256), 0, stream>>>(wsf, NBLK_P, NBLK_P);
    } else {
        main_kernel<<<dim3(NBLK_F), dim3(512), 0, stream>>>(xp, bp, bk, bv, ub, wsf);
        combine_kernel<<<dim3(27), dim3(256), 0, stream>>>(wsf, NBLK_F, NBLK_F);
    }
    final_kernel<<<dim3(1), dim3(256), 0, stream>>>(wo, bo, ln1g, ln1b, wf1, bf1, wf2, bf2,
                                                    ln2g, ln2b, wc, bc, wsf, out);
}